// Round 1
// baseline (241.141 us; speedup 1.0000x reference)
//
#include <hip/hip_runtime.h>

#define NN 100000
#define NB 196      // coarse buckets of 512 nodes (dst>>9)
#define BSHIFT 9
#define BMASK 511

typedef __attribute__((ext_vector_type(8))) short short8;
typedef __attribute__((ext_vector_type(4))) float f32x4;

__device__ __forceinline__ unsigned short f2bf(float f) {
  union { float f; unsigned int u; } v;
  v.f = f;
  unsigned int r = (v.u + 0x7fffu + ((v.u >> 16) & 1u)) >> 16;  // RNE
  return (unsigned short)r;
}
__device__ __forceinline__ float bf_lo(unsigned int u) {
  union { unsigned int u; float f; } v;
  v.u = u << 16;
  return v.f;
}
__device__ __forceinline__ float bf_hi(unsigned int u) {
  union { unsigned int u; float f; } v;
  v.u = u & 0xffff0000u;
  return v.f;
}

union SMem {
  struct {
    int cnt_l[NB];
    int start_l[NB];
    int gbase[NB];
    int wsum2[8];
    unsigned int stage[4096];
    int addr[4096];
  } b;
  struct {
    unsigned short Bs[16384];  // 32 frags x 64 lanes x 8 bf16 (fragment order)
    float Ws[256];
  } g;
};

// ---------- phase 1 (fused launch): bucket sort blocks + MFMA GEMM blocks ----------
// blocks [0,nbatch): LDS-staged coarse bucket sort (4096 edges/batch, ~84B runs).
// blocks [nbatch,..): hA16 = bf16(x @ W1) (UNSCALED) + skipout = x @ W_skip.
__global__ __launch_bounds__(512) void k_phase1(const int* __restrict__ src,
                                                const int* __restrict__ dst, int E,
                                                int cap, int* __restrict__ bcur,
                                                unsigned int* __restrict__ bkt,
                                                const float* __restrict__ x,
                                                const float* __restrict__ W1,
                                                const float* __restrict__ W_skip,
                                                unsigned short* __restrict__ hA16,
                                                float* __restrict__ skipout, int N,
                                                int nbatch) {
  __shared__ __align__(16) SMem sm;
  const int t = threadIdx.x;
  const int lane = t & 63, wid = t >> 6;

  if ((int)blockIdx.x < nbatch) {  // ---- bucket-sort branch ----
    for (int i = t; i < NB; i += 512) sm.b.cnt_l[i] = 0;
    __syncthreads();
    const int bi = blockIdx.x;
    const int e0 = bi << 12;
    unsigned int ent[8];
    int bb[8], pp[8];
#pragma unroll
    for (int j = 0; j < 8; ++j) {
      int e = e0 + j * 512 + t;
      if (e < E) {
        int d = dst[e], s = src[e];
        bb[j] = d >> BSHIFT;
        ent[j] = ((unsigned int)s << BSHIFT) | (unsigned int)(d & BMASK);
        pp[j] = atomicAdd(&sm.b.cnt_l[bb[j]], 1);
      } else {
        bb[j] = -1;
      }
    }
    __syncthreads();
    int v = (t < NB) ? sm.b.cnt_l[t] : 0;
    if (t < NB) sm.b.gbase[t] = atomicAdd(&bcur[t], v);
    int incl = v;
#pragma unroll
    for (int off = 1; off < 64; off <<= 1) {
      int u = __shfl_up(incl, off);
      if (lane >= off) incl += u;
    }
    if (lane == 63) sm.b.wsum2[wid] = incl;
    __syncthreads();
    int wpre = 0;
#pragma unroll
    for (int j = 0; j < 8; ++j) wpre += (j < wid) ? sm.b.wsum2[j] : 0;
    int tot = sm.b.wsum2[0] + sm.b.wsum2[1] + sm.b.wsum2[2] + sm.b.wsum2[3] +
              sm.b.wsum2[4] + sm.b.wsum2[5] + sm.b.wsum2[6] + sm.b.wsum2[7];
    if (t < NB) sm.b.start_l[t] = wpre + incl - v;
    __syncthreads();
#pragma unroll
    for (int j = 0; j < 8; ++j) {
      if (bb[j] >= 0) {
        int slot = sm.b.start_l[bb[j]] + pp[j];
        sm.b.stage[slot] = ent[j];
        sm.b.addr[slot] = bb[j] * cap + sm.b.gbase[bb[j]] + pp[j];
      }
    }
    __syncthreads();
    for (int s2 = t; s2 < tot; s2 += 512) bkt[sm.b.addr[s2]] = sm.b.stage[s2];
    return;
  }

  // ---- GEMM branch: 128 rows per block, 8 waves ----
  const int rb = blockIdx.x - nbatch;
#pragma unroll
  for (int it = 0; it < 4; ++it) {
    int idx = t + it * 512;  // 0..2047 fragment-lane slots
    int l2 = idx & 63, f = idx >> 6;
    int nt = f >> 2, ks = f & 3;
    int nn = nt * 16 + (l2 & 15);
    int k0 = ks * 32 + (l2 >> 4) * 8;
    unsigned short tmp[8];
#pragma unroll
    for (int j = 0; j < 8; ++j) tmp[j] = f2bf(W1[(k0 + j) * 128 + nn]);
    *(uint4*)&sm.g.Bs[idx * 8] = *(uint4*)tmp;
  }
  if (t < 256) sm.g.Ws[t] = W_skip[t];
  __syncthreads();

  const int m = lane & 15, q = lane >> 4;
  const int grow = rb * 128 + wid * 16 + m;
  const bool valid = grow < N;
  const float* xp = &x[(size_t)(valid ? grow : 0) * 128];

  f32x4 acc[8];
#pragma unroll
  for (int nt = 0; nt < 8; ++nt) acc[nt] = (f32x4){0.f, 0.f, 0.f, 0.f};
  float sk0 = 0.f, sk1 = 0.f;

#pragma unroll
  for (int ks = 0; ks < 4; ++ks) {
    short8 a;
    const int kb = ks * 32 + q * 8;
    if (valid) {
      const float* p = xp + kb;
      float4 f0 = *(const float4*)p;
      float4 f1 = *(const float4*)(p + 4);
      a[0] = (short)f2bf(f0.x); a[1] = (short)f2bf(f0.y);
      a[2] = (short)f2bf(f0.z); a[3] = (short)f2bf(f0.w);
      a[4] = (short)f2bf(f1.x); a[5] = (short)f2bf(f1.y);
      a[6] = (short)f2bf(f1.z); a[7] = (short)f2bf(f1.w);
      sk0 += f0.x * sm.g.Ws[(kb + 0) * 2] + f0.y * sm.g.Ws[(kb + 1) * 2] +
             f0.z * sm.g.Ws[(kb + 2) * 2] + f0.w * sm.g.Ws[(kb + 3) * 2] +
             f1.x * sm.g.Ws[(kb + 4) * 2] + f1.y * sm.g.Ws[(kb + 5) * 2] +
             f1.z * sm.g.Ws[(kb + 6) * 2] + f1.w * sm.g.Ws[(kb + 7) * 2];
      sk1 += f0.x * sm.g.Ws[(kb + 0) * 2 + 1] + f0.y * sm.g.Ws[(kb + 1) * 2 + 1] +
             f0.z * sm.g.Ws[(kb + 2) * 2 + 1] + f0.w * sm.g.Ws[(kb + 3) * 2 + 1] +
             f1.x * sm.g.Ws[(kb + 4) * 2 + 1] + f1.y * sm.g.Ws[(kb + 5) * 2 + 1] +
             f1.z * sm.g.Ws[(kb + 6) * 2 + 1] + f1.w * sm.g.Ws[(kb + 7) * 2 + 1];
    } else {
      a = (short8)0;
    }
#pragma unroll
    for (int nt = 0; nt < 8; ++nt) {
      short8 bfr = *(const short8*)&sm.g.Bs[((nt * 4 + ks) * 64 + lane) * 8];
      acc[nt] = __builtin_amdgcn_mfma_f32_16x16x32_bf16(a, bfr, acc[nt], 0, 0, 0);
    }
  }

  sk0 += __shfl_xor(sk0, 16); sk0 += __shfl_xor(sk0, 32);
  sk1 += __shfl_xor(sk1, 16); sk1 += __shfl_xor(sk1, 32);
  if (valid && q == 0) *(float2*)&skipout[grow * 2] = make_float2(sk0, sk1);

  const int orow = rb * 128 + wid * 16 + q * 4;
#pragma unroll
  for (int nt = 0; nt < 8; ++nt) {
    int col = nt * 16 + m;
#pragma unroll
    for (int rg = 0; rg < 4; ++rg) {
      int rr = orow + rg;
      if (rr < N) hA16[(size_t)rr * 128 + col] = f2bf(acc[nt][rg]);
    }
  }
}

// ---------- phase 2: two blocks per bucket (256-node halves) ----------
// Halved per-block atomic work, 392-block parallelism; scan pass is cheap
// sequential L2 reads with a 1-compare filter.
__global__ __launch_bounds__(512) void k_scatter(const int* __restrict__ bcur,
                                                 const unsigned int* __restrict__ bkt,
                                                 int cap, int* __restrict__ total,
                                                 int* __restrict__ ofs,
                                                 int* __restrict__ cnt,
                                                 float* __restrict__ dinv,
                                                 int* __restrict__ bin, int n) {
  __shared__ int hist[256];
  __shared__ int sofs[256];
  __shared__ int wsum[8];
  __shared__ int base;
  const int b = blockIdx.x >> 1;
  const int sub = blockIdx.x & 1;   // which 256-node half of the bucket
  const int t = threadIdx.x;
  const int lane = t & 63, wid = t >> 6;
  if (t < 256) hist[t] = 0;
  __syncthreads();
  const int m = bcur[b];
  const unsigned int* p = &bkt[(size_t)b * cap];
  for (int i = t; i < m; i += 512) {
    unsigned int u = p[i];
    int dl = u & BMASK;
    if ((dl >> 8) == sub) atomicAdd(&hist[dl & 255], 1);
  }
  __syncthreads();
  int c = (t < 256) ? hist[t] : 0;
  int cp = (c + 7) & ~7;  // pad to 8
  int incl = cp;
#pragma unroll
  for (int off = 1; off < 64; off <<= 1) {
    int u = __shfl_up(incl, off);
    if (lane >= off) incl += u;
  }
  if (lane == 63) wsum[wid] = incl;
  __syncthreads();
  if (t == 0) {
    int run = 0;
#pragma unroll
    for (int j = 0; j < 8; ++j) { int s = wsum[j]; wsum[j] = run; run += s; }
    base = atomicAdd(total, run);
  }
  __syncthreads();
  int exc = base + wsum[wid] + incl - cp;
  if (t < 256) {
    sofs[t] = exc;
    int node = (b << BSHIFT) + (sub << 8) + t;
    if (node < n) {
      ofs[node] = exc;
      cnt[node] = c;
      dinv[node] = rsqrtf((float)c + 1.0f);
    }
    hist[t] = 0;  // reuse as cursors
  }
  if (blockIdx.x == 0 && t == 300) dinv[n] = 0.f;  // dummy pad row weight
  __syncthreads();
  for (int p2 = c; p2 < cp; ++p2) bin[exc + p2] = n;  // pad with dummy zero row
  for (int i = t; i < m; i += 512) {
    unsigned int u = p[i];
    int dl = u & BMASK;
    if ((dl >> 8) == sub) {
      int pos = atomicAdd(&hist[dl & 255], 1);
      bin[sofs[dl & 255] + pos] = (int)(u >> BSHIFT);
    }
  }
}

// ---------- fused layer-1 gather: per-edge dinv fma (rows unscaled) ----------
__global__ __launch_bounds__(256) void k_gather1(const int* __restrict__ ofs,
                                                 const int* __restrict__ cnt,
                                                 const int* __restrict__ bin,
                                                 const float* __restrict__ dinv,
                                                 const uint4* __restrict__ hp,
                                                 const float* __restrict__ b1,
                                                 const float* __restrict__ W2,
                                                 float* __restrict__ t2s, int N) {
  int d = blockIdx.x * 4 + (threadIdx.x >> 6);
  if (d >= N) return;
  const int lane = threadIdx.x & 63;
  const int rg = lane >> 4;
  const int fl = lane & 15;
  const int beg = ofs[d];
  const int np = (cnt[d] + 7) & ~7;

  const float dd = dinv[d];
  uint4 vs = hp[(size_t)d * 16 + fl];
  float4 b1a = *(const float4*)&b1[fl * 8];
  float4 b1b = *(const float4*)&b1[fl * 8 + 4];
  float4 wa = *(const float4*)&W2[fl * 16];
  float4 wb = *(const float4*)&W2[fl * 16 + 4];
  float4 wc = *(const float4*)&W2[fl * 16 + 8];
  float4 wd = *(const float4*)&W2[fl * 16 + 12];

  float acc[8] = {};
  for (int e0 = 0; e0 < np; e0 += 8) {
    int s0 = bin[beg + e0 + rg];
    int s1 = bin[beg + e0 + 4 + rg];
    float w0 = dinv[s0];
    float w1 = dinv[s1];
    uint4 v0 = hp[(size_t)s0 * 16 + fl];
    uint4 v1 = hp[(size_t)s1 * 16 + fl];
    acc[0] = fmaf(w0, bf_lo(v0.x), acc[0]); acc[1] = fmaf(w0, bf_hi(v0.x), acc[1]);
    acc[2] = fmaf(w0, bf_lo(v0.y), acc[2]); acc[3] = fmaf(w0, bf_hi(v0.y), acc[3]);
    acc[4] = fmaf(w0, bf_lo(v0.z), acc[4]); acc[5] = fmaf(w0, bf_hi(v0.z), acc[5]);
    acc[6] = fmaf(w0, bf_lo(v0.w), acc[6]); acc[7] = fmaf(w0, bf_hi(v0.w), acc[7]);
    acc[0] = fmaf(w1, bf_lo(v1.x), acc[0]); acc[1] = fmaf(w1, bf_hi(v1.x), acc[1]);
    acc[2] = fmaf(w1, bf_lo(v1.y), acc[2]); acc[3] = fmaf(w1, bf_hi(v1.y), acc[3]);
    acc[4] = fmaf(w1, bf_lo(v1.z), acc[4]); acc[5] = fmaf(w1, bf_hi(v1.z), acc[5]);
    acc[6] = fmaf(w1, bf_lo(v1.w), acc[6]); acc[7] = fmaf(w1, bf_hi(v1.w), acc[7]);
  }
#pragma unroll
  for (int j = 0; j < 8; ++j) {
    acc[j] += __shfl_xor(acc[j], 16);
    acc[j] += __shfl_xor(acc[j], 32);
  }
  // self-loop: + dinv[d] * h[d]
  acc[0] = fmaf(dd, bf_lo(vs.x), acc[0]); acc[1] = fmaf(dd, bf_hi(vs.x), acc[1]);
  acc[2] = fmaf(dd, bf_lo(vs.y), acc[2]); acc[3] = fmaf(dd, bf_hi(vs.y), acc[3]);
  acc[4] = fmaf(dd, bf_lo(vs.z), acc[4]); acc[5] = fmaf(dd, bf_hi(vs.z), acc[5]);
  acc[6] = fmaf(dd, bf_lo(vs.w), acc[6]); acc[7] = fmaf(dd, bf_hi(vs.w), acc[7]);

  float vj[8];
  vj[0] = fmaxf(acc[0] * dd + b1a.x, 0.f);
  vj[1] = fmaxf(acc[1] * dd + b1a.y, 0.f);
  vj[2] = fmaxf(acc[2] * dd + b1a.z, 0.f);
  vj[3] = fmaxf(acc[3] * dd + b1a.w, 0.f);
  vj[4] = fmaxf(acc[4] * dd + b1b.x, 0.f);
  vj[5] = fmaxf(acc[5] * dd + b1b.y, 0.f);
  vj[6] = fmaxf(acc[6] * dd + b1b.z, 0.f);
  vj[7] = fmaxf(acc[7] * dd + b1b.w, 0.f);
  float p0 = vj[0] * wa.x + vj[1] * wa.z + vj[2] * wb.x + vj[3] * wb.z +
             vj[4] * wc.x + vj[5] * wc.z + vj[6] * wd.x + vj[7] * wd.z;
  float p1 = vj[0] * wa.y + vj[1] * wa.w + vj[2] * wb.y + vj[3] * wb.w +
             vj[4] * wc.y + vj[5] * wc.w + vj[6] * wd.y + vj[7] * wd.w;
#pragma unroll
  for (int off = 1; off < 16; off <<= 1) {
    p0 += __shfl_xor(p0, off);
    p1 += __shfl_xor(p1, off);
  }
  if (lane == 0) *(float2*)&t2s[d * 2] = make_float2(p0 * dd, p1 * dd);
}

// ---------- final: out = dinv[i]*(sum_s t2s[s] + t2s[i]) + b2 + skip + b_skip -----
__global__ __launch_bounds__(256) void k_final(const float* __restrict__ b_skip,
                                               const float* __restrict__ b2,
                                               const float* __restrict__ t2s,
                                               const float* __restrict__ skipout,
                                               const float* __restrict__ dinv,
                                               const int* __restrict__ ofs,
                                               const int* __restrict__ cnt,
                                               const int* __restrict__ bin,
                                               float* __restrict__ out, int N) {
  int i = blockIdx.x * 4 + (threadIdx.x >> 6);
  if (i >= N) return;
  const int lane = threadIdx.x & 63;
  const int beg = ofs[i], end = beg + cnt[i];  // real count (skip pads)
  float g0 = 0.f, g1 = 0.f;
  for (int e = beg + lane; e < end; e += 64) {
    int s = bin[e];
    float2 t = *(const float2*)&t2s[s * 2];
    g0 += t.x; g1 += t.y;
  }
#pragma unroll
  for (int off = 32; off > 0; off >>= 1) {
    g0 += __shfl_down(g0, off);
    g1 += __shfl_down(g1, off);
  }
  if (lane == 0) {
    float di = dinv[i];
    float2 ts = *(const float2*)&t2s[i * 2];
    float2 sk = *(const float2*)&skipout[i * 2];
    float o0 = di * (g0 + ts.x) + b2[0] + sk.x + b_skip[0];
    float o1 = di * (g1 + ts.y) + b2[1] + sk.y + b_skip[1];
    *(float2*)&out[i * 2] = make_float2(o0, o1);
  }
}

extern "C" void kernel_launch(void* const* d_in, const int* in_sizes, int n_in,
                              void* d_out, int out_size, void* d_ws, size_t ws_size,
                              hipStream_t stream) {
  const float* x      = (const float*)d_in[0];
  const int*   edges  = (const int*)d_in[1];
  const float* W1     = (const float*)d_in[2];
  const float* b1     = (const float*)d_in[3];
  const float* W2     = (const float*)d_in[4];
  const float* b2     = (const float*)d_in[5];
  const float* W_skip = (const float*)d_in[6];
  const float* b_skip = (const float*)d_in[7];
  float* out = (float*)d_out;

  const int N = NN;
  const int E = in_sizes[1] / 2;
  const int* src = edges;
  const int* dst = edges + E;
  const size_t BINCAP = (size_t)E + 8 * (size_t)N;  // pad-to-8 capacity
  const int CAP = ((E / NB) + 896 + 255) & ~255;    // per-bucket capacity (~10 sigma)

  // ws layout: [hA16 (N+1)*128 u16][bcur NB][total 4][ofs N+4][dinv N+8][cnt N]
  //            [bkt NB*CAP u32][bin BINCAP][t2s 2N][skipout 2N]
  unsigned short* hA16 = (unsigned short*)d_ws;
  int*   bcur    = (int*)(hA16 + (size_t)(NN + 1) * 128);
  int*   total   = bcur + NB;
  int*   ofs     = total + 4;
  float* dinv    = (float*)(ofs + N + 4);
  int*   cnt     = (int*)(dinv + N + 8);
  unsigned int* bkt = (unsigned int*)(cnt + N);
  int*   bin     = (int*)(bkt + (size_t)NB * CAP);
  float* t2s     = (float*)(bin + BINCAP);
  float* skipout = t2s + 2 * (size_t)N;

  // zero: dummy hA16 row (256B) + bcur + total, contiguous
  hipMemsetAsync(hA16 + (size_t)N * 128, 0, 256 + (NB + 4) * sizeof(int), stream);

  const int nbatch = (E + 4095) / 4096;
  const int gemmb = (N + 127) / 128;
  k_phase1<<<nbatch + gemmb, 512, 0, stream>>>(src, dst, E, CAP, bcur, bkt, x, W1,
                                               W_skip, hA16, skipout, N, nbatch);
  k_scatter<<<2 * NB, 512, 0, stream>>>(bcur, bkt, CAP, total, ofs, cnt, dinv, bin, N);
  k_gather1<<<(N + 3) / 4, 256, 0, stream>>>(ofs, cnt, bin, dinv, (const uint4*)hA16,
                                             b1, W2, t2s, N);
  k_final<<<(N + 3) / 4, 256, 0, stream>>>(b_skip, b2, t2s, skipout, dinv, ofs, cnt,
                                           bin, out, N);
}